// Round 3
// baseline (169.830 us; speedup 1.0000x reference)
//
#include <hip/hip_runtime.h>
#include <hip/hip_bf16.h>

typedef __attribute__((ext_vector_type(8))) short bf16x8;
typedef __attribute__((ext_vector_type(4))) float f32x4;

// RNE float -> bf16 bits
static __device__ __forceinline__ ushort f2b(float f) {
    unsigned u = __float_as_uint(f);
    return (ushort)((u + 0x7fffu + ((u >> 16) & 1u)) >> 16);
}

static __device__ __forceinline__ void gload16(const void* g, void* lds) {
    __builtin_amdgcn_global_load_lds(
        (const __attribute__((address_space(1))) unsigned int*)g,
        (__attribute__((address_space(3))) unsigned int*)lds, 16, 0, 0);
}

// ---------------------------------------------------------------------------
// prep: per (b,d) row of x[64][256][196]: mean-center, write bf16 into
// xc[64][256][256] (k=196..255 zero), var_d (+1e-7) per row for the trace.
// ---------------------------------------------------------------------------
__global__ __launch_bounds__(256) void prep_kernel(
    const float* __restrict__ x, ushort* __restrict__ xc, float* __restrict__ var)
{
    const int t = threadIdx.x, wv = t >> 6, l = t & 63;
    const int rowid = blockIdx.x * 4 + wv;     // b*256 + d
    const float* xr = x + (size_t)rowid * 196;

    float x0 = xr[l];
    float x1 = xr[l + 64];
    float x2 = xr[l + 128];
    float x3 = (l < 4) ? xr[l + 192] : 0.0f;

    float s1 = x0 + x1 + x2 + x3;
    float s2 = x0*x0 + x1*x1 + x2*x2 + x3*x3;
    #pragma unroll
    for (int off = 32; off; off >>= 1) {
        s1 += __shfl_xor(s1, off);
        s2 += __shfl_xor(s2, off);
    }
    const float mean = s1 * (1.0f / 196.0f);
    if (l == 0) var[rowid] = s2 * (1.0f / 196.0f) - mean * mean + 1e-7f;

    ushort* xcr = xc + (size_t)rowid * 256;
    xcr[l]       = f2b(x0 - mean);
    xcr[l + 64]  = f2b(x1 - mean);
    xcr[l + 128] = f2b(x2 - mean);
    xcr[l + 192] = (l < 4) ? f2b(x3 - mean) : (ushort)0;   // zero pad 196..255
}

// ---------------------------------------------------------------------------
// Batched NT GEMM on symmetric operands, 128x64 tile, BK=32, 4 waves (2x2,
// each wave 64x32), global_load_lds staging, 2-phase double-buffer. K = 256.
// MODE 0: cov : C = Y0 = (acc/196 + 1e-7 I)/trace[b];  C2 = 1.5I - 0.5*Y0
// MODE 1: T   : C = 1.5I - 0.5*acc
// MODE 2: pair: bb<64: C = A*Bt^T;  bb>=64: C2 = A2*Bt^T
// MODE 3: tri : lower-tri of acc*sqrt(trace[b]) -> C (6 tiles only)
// ---------------------------------------------------------------------------
template<int MODE>
__global__ __launch_bounds__(256) void gemm_ns(
    const ushort* __restrict__ A, const ushort* __restrict__ A2,
    const ushort* __restrict__ Bt,
    ushort* __restrict__ C, ushort* __restrict__ C2,
    const float* __restrict__ var)
{
    __shared__ ushort As[2][128][32];   // 16 KB
    __shared__ ushort Bs[2][64][32];    //  8 KB
    __shared__ float tr_s[4];

    const int bb = blockIdx.y, b = bb & 63;
    const int bx = blockIdx.x;
    int i0, j0;
    if (MODE == 3) {               // 6 lower-triangle tiles
        i0 = (bx >= 2) ? 128 : 0;
        j0 = (bx < 2) ? bx * 64 : (bx - 2) * 64;
    } else {
        i0 = (bx >> 2) * 128;
        j0 = (bx & 3) * 64;
    }
    const ushort* Ab  = ((MODE == 2 && bb >= 64) ? A2 : A) + (size_t)b * 65536;
    const ushort* Btb = Bt + (size_t)b * 65536;

    const int t  = threadIdx.x, wv = t >> 6, l = t & 63;
    const int li = l & 15, hi = l >> 4;
    const int wr = wv >> 1, wc = wv & 1;
    const int srow = wv * 16 + (l >> 2);   // staging row within 64-row chunk
    const int scol = (l & 3) * 8;          // staging col (elements)

    f32x4 acc[4][2];
    #pragma unroll
    for (int m = 0; m < 4; ++m)
        #pragma unroll
        for (int n = 0; n < 2; ++n) acc[m][n] = (f32x4){0.f, 0.f, 0.f, 0.f};

#define STAGE(bufo, kk) do {                                                        \
    gload16(Ab  + (size_t)(i0 +      srow) * 256 + (kk) + scol,                     \
            (char*)&As[bufo][0][0] + wv * 1024);                                    \
    gload16(Ab  + (size_t)(i0 + 64 + srow) * 256 + (kk) + scol,                     \
            (char*)&As[bufo][0][0] + 4096 + wv * 1024);                             \
    gload16(Btb + (size_t)(j0 +      srow) * 256 + (kk) + scol,                     \
            (char*)&Bs[bufo][0][0] + wv * 1024);                                    \
} while (0)

    STAGE(0, 0);
    // fold the trace reduction under the first staging barrier
    if (MODE == 0 || MODE == 3) {
        float v = var[b * 256 + t];
        #pragma unroll
        for (int off = 32; off; off >>= 1) v += __shfl_xor(v, off);
        if (l == 0) tr_s[wv] = v;
    }
    __syncthreads();
    float trace = 0.f;
    if (MODE == 0 || MODE == 3) trace = tr_s[0] + tr_s[1] + tr_s[2] + tr_s[3];

    #pragma unroll
    for (int tk = 0; tk < 8; ++tk) {
        const int bo = tk & 1;
        if (tk < 7) STAGE(bo ^ 1, (tk + 1) * 32);
        bf16x8 af[4], bfr[2];
        #pragma unroll
        for (int m = 0; m < 4; ++m)
            af[m] = *(const bf16x8*)&As[bo][wr * 64 + m * 16 + li][hi * 8];
        #pragma unroll
        for (int n = 0; n < 2; ++n)
            bfr[n] = *(const bf16x8*)&Bs[bo][wc * 32 + n * 16 + li][hi * 8];
        #pragma unroll
        for (int m = 0; m < 4; ++m)
            #pragma unroll
            for (int n = 0; n < 2; ++n)
                acc[m][n] = __builtin_amdgcn_mfma_f32_16x16x32_bf16(
                    af[m], bfr[n], acc[m][n], 0, 0, 0);
        __syncthreads();
    }
#undef STAGE

    if (MODE == 3) {
        const float sc = sqrtf(trace);
        ushort* trib = C + (size_t)b * 32896;
        #pragma unroll
        for (int m = 0; m < 4; ++m)
            #pragma unroll
            for (int n = 0; n < 2; ++n)
                #pragma unroll
                for (int r = 0; r < 4; ++r) {
                    const int gi = i0 + wr * 64 + m * 16 + hi * 4 + r;
                    const int gj = j0 + wc * 32 + n * 16 + li;
                    if (gj <= gi)
                        trib[(gi * (gi + 1)) / 2 + gj] = f2b(acc[m][n][r] * sc);
                }
    } else {
        const float invtr = (MODE == 0) ? (1.0f / trace) : 0.0f;
        ushort* Cb  = ((MODE == 2 && bb >= 64) ? C2 : C) + (size_t)b * 65536;
        ushort* C2b = (MODE == 0) ? (C2 + (size_t)b * 65536) : nullptr;
        #pragma unroll
        for (int m = 0; m < 4; ++m)
            #pragma unroll
            for (int n = 0; n < 2; ++n)
                #pragma unroll
                for (int r = 0; r < 4; ++r) {
                    const int gi = i0 + wr * 64 + m * 16 + hi * 4 + r;
                    const int gj = j0 + wc * 32 + n * 16 + li;
                    const float v = acc[m][n][r];
                    const size_t idx = (size_t)gi * 256 + gj;
                    if (MODE == 0) {
                        float y0 = (v * (1.0f / 196.0f) + ((gi == gj) ? 1e-7f : 0.0f)) * invtr;
                        Cb[idx]  = f2b(y0);
                        C2b[idx] = f2b(((gi == gj) ? 1.5f : 0.0f) - 0.5f * y0);
                    } else if (MODE == 1) {
                        Cb[idx] = f2b(((gi == gj) ? 1.5f : 0.0f) - 0.5f * v);
                    } else {
                        Cb[idx] = f2b(v);
                    }
                }
    }
}

// ---------------------------------------------------------------------------
// FC: partial[split][64][384] = tri[64][K] * W[365][K]^T over this split's K
// ---------------------------------------------------------------------------
__global__ __launch_bounds__(256) void fc_gemm(
    const ushort* __restrict__ tri, const float* __restrict__ W,
    float* __restrict__ partial)
{
    __shared__ ushort As[64][40];
    __shared__ ushort Bs[64][40];

    const int ntile = blockIdx.x;              // 0..5
    const int split = blockIdx.y;              // 0..63
    const int steps = 16 + (split < 4 ? 1 : 0);
    const int step0 = split * 16 + (split < 4 ? split : 4);

    const int t   = threadIdx.x;
    const int row = t >> 2, seg = t & 3;
    const int wv  = t >> 6, l = t & 63;
    const int li  = l & 15, hi = l >> 4;
    const int n   = ntile * 64 + row;

    f32x4 acc[4];
    #pragma unroll
    for (int c = 0; c < 4; ++c) acc[c] = (f32x4){0.f, 0.f, 0.f, 0.f};

    for (int s = 0; s < steps; ++s) {
        const int kk = (step0 + s) * 32;
        *(bf16x8*)&As[row][seg * 8] =
            *(const bf16x8*)(tri + (size_t)row * 32896 + kk + seg * 8);
        bf16x8 pk;
        if (n < 365) {
            const float* wp = W + (size_t)n * 32896 + kk + seg * 8;
            float4 f0 = *(const float4*)wp;
            float4 f1 = *(const float4*)(wp + 4);
            pk[0] = (short)f2b(f0.x); pk[1] = (short)f2b(f0.y);
            pk[2] = (short)f2b(f0.z); pk[3] = (short)f2b(f0.w);
            pk[4] = (short)f2b(f1.x); pk[5] = (short)f2b(f1.y);
            pk[6] = (short)f2b(f1.z); pk[7] = (short)f2b(f1.w);
        } else {
            pk = (bf16x8){0,0,0,0,0,0,0,0};
        }
        *(bf16x8*)&Bs[row][seg * 8] = pk;
        __syncthreads();
        bf16x8 a = *(const bf16x8*)&As[wv * 16 + li][hi * 8];
        #pragma unroll
        for (int c = 0; c < 4; ++c) {
            bf16x8 bb = *(const bf16x8*)&Bs[c * 16 + li][hi * 8];
            acc[c] = __builtin_amdgcn_mfma_f32_16x16x32_bf16(a, bb, acc[c], 0, 0, 0);
        }
        __syncthreads();
    }

    #pragma unroll
    for (int c = 0; c < 4; ++c) {
        #pragma unroll
        for (int r = 0; r < 4; ++r) {
            const int i = wv * 16 + hi * 4 + r;          // batch
            const int j = ntile * 64 + c * 16 + li;      // class
            partial[((size_t)split * 64 + i) * 384 + j] = acc[c][r];
        }
    }
}

__global__ void fc_reduce(const float* __restrict__ partial,
                          const float* __restrict__ bias, float* __restrict__ out)
{
    const int idx = blockIdx.x * 256 + threadIdx.x;
    if (idx >= 64 * 365) return;
    const int b = idx / 365, n = idx % 365;
    float s = bias[n];
    #pragma unroll 4
    for (int sp = 0; sp < 64; ++sp)
        s += partial[((size_t)sp * 64 + b) * 384 + n];
    out[idx] = s;
}

// ---------------------------------------------------------------------------
extern "C" void kernel_launch(void* const* d_in, const int* in_sizes, int n_in,
                              void* d_out, int out_size, void* d_ws, size_t ws_size,
                              hipStream_t stream)
{
    const float* x   = (const float*)d_in[0];
    const float* fcw = (const float*)d_in[1];
    const float* fcb = (const float*)d_in[2];
    float* out = (float*)d_out;
    char* ws = (char*)d_ws;

    const size_t MS = (size_t)64 * 256 * 256 * 2;   // 8 MiB per matrix buffer
    ushort* w0 = (ushort*)(ws + 0 * MS);
    ushort* w1 = (ushort*)(ws + 1 * MS);
    ushort* w2 = (ushort*)(ws + 2 * MS);
    ushort* w3 = (ushort*)(ws + 3 * MS);
    ushort* w4 = (ushort*)(ws + 4 * MS);
    ushort* xc = (ushort*)(ws + 5 * MS);                     // 8 MiB (padded K=256)
    float*  var    = (float*)(ws + 6 * MS);                  // 65,536 B
    ushort* tri    = (ushort*)(ws + 6 * MS + 131072);        // 4,210,688 B
    float*  partial= (float*)(ws + 6 * MS + 131072 + 4210688);

    prep_kernel<<<4096, 256, 0, stream>>>(x, xc, var);

    dim3 g1(8, 64), g2(8, 128);
    // cov: Y0 -> w0, T0 (= Z1-role T) -> w1
    gemm_ns<0><<<g1, 256, 0, stream>>>(xc, nullptr, xc, w0, w1, var);
    // Y1 = Y0*T0 -> w2
    gemm_ns<2><<<g1, 256, 0, stream>>>(w0, nullptr, w1, w2, nullptr, nullptr);
    // iter2 (Y=w2, Z=w1): T -> w0 ; Y'=Y*T -> w3 ; Z'=Z*T -> w4
    gemm_ns<1><<<g1, 256, 0, stream>>>(w1, nullptr, w2, w0, nullptr, nullptr);
    gemm_ns<2><<<g2, 256, 0, stream>>>(w2, w1, w0, w3, w4, nullptr);
    // iter3 (Y=w3, Z=w4): T -> w0 ; Y' -> w1 ; Z' -> w2
    gemm_ns<1><<<g1, 256, 0, stream>>>(w4, nullptr, w3, w0, nullptr, nullptr);
    gemm_ns<2><<<g2, 256, 0, stream>>>(w3, w4, w0, w1, w2, nullptr);
    // iter4 (Y=w1, Z=w2): T -> w0 ; Y' -> w3 ; Z' -> w4
    gemm_ns<1><<<g1, 256, 0, stream>>>(w2, nullptr, w1, w0, nullptr, nullptr);
    gemm_ns<2><<<g2, 256, 0, stream>>>(w1, w2, w0, w3, w4, nullptr);
    // iter5 (Y=w3, Z=w4): T -> w0 ; tri(Y*T*sqrt(trace)) -> tri
    gemm_ns<1><<<g1, 256, 0, stream>>>(w4, nullptr, w3, w0, nullptr, nullptr);
    gemm_ns<3><<<dim3(6, 64), 256, 0, stream>>>(w3, nullptr, w0, tri, nullptr, var);

    fc_gemm<<<dim3(6, 64), 256, 0, stream>>>(tri, fcw, partial);
    fc_reduce<<<(64 * 365 + 255) / 256, 256, 0, stream>>>(partial, fcb, out);
}

// Round 4
// 124.347 us; speedup vs baseline: 1.3658x; 1.3658x over previous
//
#include <hip/hip_runtime.h>
#include <hip/hip_bf16.h>

typedef __attribute__((ext_vector_type(8))) short bf16x8;
typedef __attribute__((ext_vector_type(4))) float f32x4;

// RNE float -> bf16 bits
static __device__ __forceinline__ ushort f2b(float f) {
    unsigned u = __float_as_uint(f);
    return (ushort)((u + 0x7fffu + ((u >> 16) & 1u)) >> 16);
}

static __device__ __forceinline__ void gload16(const void* g, void* lds) {
    __builtin_amdgcn_global_load_lds(
        (const __attribute__((address_space(1))) unsigned int*)g,
        (__attribute__((address_space(3))) unsigned int*)lds, 16, 0, 0);
}

// ---------------------------------------------------------------------------
// prep: per (b,d) row of x[64][256][196]: mean-center, write bf16 into
// xc[64][256][256] (k=196..255 zero), var_d (+1e-7) per row for the trace.
// XCD-pinned: blockIdx%8 == batch%8.
// ---------------------------------------------------------------------------
__global__ __launch_bounds__(256) void prep_kernel(
    const float* __restrict__ x, ushort* __restrict__ xc, float* __restrict__ var)
{
    const int t = threadIdx.x, wv = t >> 6, l = t & 63;
    const int bid = blockIdx.x;
    const int x8 = bid & 7, rr = bid >> 3;
    const int dgrp = rr & 63, bgrp = rr >> 6;
    const int b = bgrp * 8 + x8;
    const int rowid = b * 256 + dgrp * 4 + wv;
    const float* xr = x + (size_t)rowid * 196;

    float x0 = xr[l];
    float x1 = xr[l + 64];
    float x2 = xr[l + 128];
    float x3 = (l < 4) ? xr[l + 192] : 0.0f;

    float s1 = x0 + x1 + x2 + x3;
    float s2 = x0*x0 + x1*x1 + x2*x2 + x3*x3;
    #pragma unroll
    for (int off = 32; off; off >>= 1) {
        s1 += __shfl_xor(s1, off);
        s2 += __shfl_xor(s2, off);
    }
    const float mean = s1 * (1.0f / 196.0f);
    if (l == 0) var[rowid] = s2 * (1.0f / 196.0f) - mean * mean + 1e-7f;

    ushort* xcr = xc + (size_t)rowid * 256;
    xcr[l]       = f2b(x0 - mean);
    xcr[l + 64]  = f2b(x1 - mean);
    xcr[l + 128] = f2b(x2 - mean);
    xcr[l + 192] = (l < 4) ? f2b(x3 - mean) : (ushort)0;   // zero pad 196..255
}

// ---------------------------------------------------------------------------
// Batched NT GEMM on symmetric operands. 128x128 tile, whole K=256 resident
// in LDS (tk-major [8][128][32] slabs), 4 waves (2x2, 64x64/wave),
// global_load_lds staging in two halves overlapped with compute.
// MODE 0: cov  : C = Y0 = (acc/196 + 1e-7 I)/trace[b];  C2 = 1.5I - 0.5*Y0
// MODE 1: T    : C = 1.5I - 0.5*acc
// MODE 2: pair : half grid: C = A*Bt^T; other half: C2 = A2*Bt^T
// MODE 3: tri  : lower-tri of acc*sqrt(trace[b]) -> C (3 tiles)
// MODE 4: plain: C = acc
// XCD-pinned: blockIdx%8 == batch%8 for every mode.
// ---------------------------------------------------------------------------
template<int H>
static __device__ __forceinline__ void stage_half(
    const ushort* Ab, const ushort* Btb, int i0, int j0,
    int wv, int lrow, int seg, ushort* As, ushort* Bs)
{
    #pragma unroll
    for (int it = 0; it < 8; ++it) {
        const int c = H * 32 + wv * 8 + it;       // chunk 0..63
        const int tk = c >> 3, r16 = c & 7;
        const int row = r16 * 16 + lrow;
        gload16(Ab + (size_t)(i0 + row) * 256 + tk * 32 + seg,
                (char*)As + tk * 8192 + r16 * 1024);
        gload16(Btb + (size_t)(j0 + row) * 256 + tk * 32 + seg,
                (char*)Bs + tk * 8192 + r16 * 1024);
    }
}

template<int MODE>
__global__ __launch_bounds__(256) void gemm_ns(
    const ushort* __restrict__ A, const ushort* __restrict__ A2,
    const ushort* __restrict__ Bt,
    ushort* __restrict__ C, ushort* __restrict__ C2,
    const float* __restrict__ var)
{
    __shared__ ushort As[8][128][32];   // 64 KB, tk-major slabs
    __shared__ ushort Bs[8][128][32];   // 64 KB
    __shared__ float tr_s[4];

    const int bid = blockIdx.x, x8 = bid & 7;
    int b, i0, j0;
    bool useA2 = false;
    if (MODE == 2) {
        const int tt = (bid >> 3) & 3;
        useA2 = ((bid >> 5) & 1) != 0;
        b = (bid >> 6) * 8 + x8;
        i0 = (tt >> 1) * 128; j0 = (tt & 1) * 128;
    } else if (MODE == 3) {
        const int rr = bid >> 3, t3 = rr % 3;
        b = (rr / 3) * 8 + x8;
        i0 = (t3 == 0) ? 0 : 128;
        j0 = (t3 == 2) ? 128 : 0;
    } else {
        const int tt = (bid >> 3) & 3;
        b = (bid >> 5) * 8 + x8;
        i0 = (tt >> 1) * 128; j0 = (tt & 1) * 128;
    }
    const ushort* Ab  = (useA2 ? A2 : A) + (size_t)b * 65536;
    const ushort* Btb = Bt + (size_t)b * 65536;

    const int t = threadIdx.x, wv = t >> 6, l = t & 63;
    const int li = l & 15, hi = l >> 4;
    const int wr = wv >> 1, wc = wv & 1;
    const int lrow = l >> 2;           // row within 16-row staging chunk
    const int seg = (l & 3) * 8;       // col offset in elements

    stage_half<0>(Ab, Btb, i0, j0, wv, lrow, seg, &As[0][0][0], &Bs[0][0][0]);

    // fold the per-batch trace reduction under the first staging wait
    if (MODE == 0 || MODE == 3) {
        float v = var[b * 256 + t];
        #pragma unroll
        for (int off = 32; off; off >>= 1) v += __shfl_xor(v, off);
        if (l == 0) tr_s[wv] = v;
    }
    __syncthreads();
    float trace = 0.f;
    if (MODE == 0 || MODE == 3) trace = tr_s[0] + tr_s[1] + tr_s[2] + tr_s[3];

    f32x4 acc[4][4];
    #pragma unroll
    for (int m = 0; m < 4; ++m)
        #pragma unroll
        for (int n = 0; n < 4; ++n) acc[m][n] = (f32x4){0.f, 0.f, 0.f, 0.f};

    stage_half<1>(Ab, Btb, i0, j0, wv, lrow, seg, &As[0][0][0], &Bs[0][0][0]);

    #pragma unroll
    for (int tk = 0; tk < 4; ++tk) {
        bf16x8 af[4], bfr[4];
        #pragma unroll
        for (int m = 0; m < 4; ++m)
            af[m] = *(const bf16x8*)&As[tk][wr * 64 + m * 16 + li][hi * 8];
        #pragma unroll
        for (int n = 0; n < 4; ++n)
            bfr[n] = *(const bf16x8*)&Bs[tk][wc * 64 + n * 16 + li][hi * 8];
        #pragma unroll
        for (int m = 0; m < 4; ++m)
            #pragma unroll
            for (int n = 0; n < 4; ++n)
                acc[m][n] = __builtin_amdgcn_mfma_f32_16x16x32_bf16(
                    af[m], bfr[n], acc[m][n], 0, 0, 0);
    }
    __syncthreads();
    #pragma unroll
    for (int tk = 4; tk < 8; ++tk) {
        bf16x8 af[4], bfr[4];
        #pragma unroll
        for (int m = 0; m < 4; ++m)
            af[m] = *(const bf16x8*)&As[tk][wr * 64 + m * 16 + li][hi * 8];
        #pragma unroll
        for (int n = 0; n < 4; ++n)
            bfr[n] = *(const bf16x8*)&Bs[tk][wc * 64 + n * 16 + li][hi * 8];
        #pragma unroll
        for (int m = 0; m < 4; ++m)
            #pragma unroll
            for (int n = 0; n < 4; ++n)
                acc[m][n] = __builtin_amdgcn_mfma_f32_16x16x32_bf16(
                    af[m], bfr[n], acc[m][n], 0, 0, 0);
    }

    if (MODE == 3) {
        const float sc = sqrtf(trace);
        ushort* trib = C + (size_t)b * 32896;
        #pragma unroll
        for (int m = 0; m < 4; ++m)
            #pragma unroll
            for (int n = 0; n < 4; ++n)
                #pragma unroll
                for (int r = 0; r < 4; ++r) {
                    const int gi = i0 + wr * 64 + m * 16 + hi * 4 + r;
                    const int gj = j0 + wc * 64 + n * 16 + li;
                    if (gj <= gi)
                        trib[(gi * (gi + 1)) / 2 + gj] = f2b(acc[m][n][r] * sc);
                }
    } else {
        const float invtr = (MODE == 0) ? (1.0f / trace) : 0.0f;
        ushort* Cb  = ((MODE == 2 && useA2) ? C2 : C) + (size_t)b * 65536;
        ushort* C2b = (MODE == 0) ? (C2 + (size_t)b * 65536) : nullptr;
        #pragma unroll
        for (int m = 0; m < 4; ++m)
            #pragma unroll
            for (int n = 0; n < 4; ++n)
                #pragma unroll
                for (int r = 0; r < 4; ++r) {
                    const int gi = i0 + wr * 64 + m * 16 + hi * 4 + r;
                    const int gj = j0 + wc * 64 + n * 16 + li;
                    const float v = acc[m][n][r];
                    const size_t idx = (size_t)gi * 256 + gj;
                    if (MODE == 0) {
                        float y0 = (v * (1.0f / 196.0f) + ((gi == gj) ? 1e-7f : 0.0f)) * invtr;
                        Cb[idx]  = f2b(y0);
                        C2b[idx] = f2b(((gi == gj) ? 1.5f : 0.0f) - 0.5f * y0);
                    } else if (MODE == 1) {
                        Cb[idx] = f2b(((gi == gj) ? 1.5f : 0.0f) - 0.5f * v);
                    } else {
                        Cb[idx] = f2b(v);
                    }
                }
    }
}

// ---------------------------------------------------------------------------
// FC: partial[split][64][384] = tri[64][K] * W[365][K]^T over this split's K
// ---------------------------------------------------------------------------
__global__ __launch_bounds__(256) void fc_gemm(
    const ushort* __restrict__ tri, const float* __restrict__ W,
    float* __restrict__ partial)
{
    __shared__ ushort As[64][40];
    __shared__ ushort Bs[64][40];

    const int ntile = blockIdx.x;              // 0..5
    const int split = blockIdx.y;              // 0..63
    const int steps = 16 + (split < 4 ? 1 : 0);
    const int step0 = split * 16 + (split < 4 ? split : 4);

    const int t   = threadIdx.x;
    const int row = t >> 2, seg = t & 3;
    const int wv  = t >> 6, l = t & 63;
    const int li  = l & 15, hi = l >> 4;
    const int n   = ntile * 64 + row;

    f32x4 acc[4];
    #pragma unroll
    for (int c = 0; c < 4; ++c) acc[c] = (f32x4){0.f, 0.f, 0.f, 0.f};

    for (int s = 0; s < steps; ++s) {
        const int kk = (step0 + s) * 32;
        *(bf16x8*)&As[row][seg * 8] =
            *(const bf16x8*)(tri + (size_t)row * 32896 + kk + seg * 8);
        bf16x8 pk;
        if (n < 365) {
            const float* wp = W + (size_t)n * 32896 + kk + seg * 8;
            float4 f0 = *(const float4*)wp;
            float4 f1 = *(const float4*)(wp + 4);
            pk[0] = (short)f2b(f0.x); pk[1] = (short)f2b(f0.y);
            pk[2] = (short)f2b(f0.z); pk[3] = (short)f2b(f0.w);
            pk[4] = (short)f2b(f1.x); pk[5] = (short)f2b(f1.y);
            pk[6] = (short)f2b(f1.z); pk[7] = (short)f2b(f1.w);
        } else {
            pk = (bf16x8){0,0,0,0,0,0,0,0};
        }
        *(bf16x8*)&Bs[row][seg * 8] = pk;
        __syncthreads();
        bf16x8 a = *(const bf16x8*)&As[wv * 16 + li][hi * 8];
        #pragma unroll
        for (int c = 0; c < 4; ++c) {
            bf16x8 bb = *(const bf16x8*)&Bs[c * 16 + li][hi * 8];
            acc[c] = __builtin_amdgcn_mfma_f32_16x16x32_bf16(a, bb, acc[c], 0, 0, 0);
        }
        __syncthreads();
    }

    #pragma unroll
    for (int c = 0; c < 4; ++c) {
        #pragma unroll
        for (int r = 0; r < 4; ++r) {
            const int i = wv * 16 + hi * 4 + r;          // batch
            const int j = ntile * 64 + c * 16 + li;      // class
            partial[((size_t)split * 64 + i) * 384 + j] = acc[c][r];
        }
    }
}

__global__ void fc_reduce(const float* __restrict__ partial,
                          const float* __restrict__ bias, float* __restrict__ out)
{
    const int idx = blockIdx.x * 256 + threadIdx.x;
    if (idx >= 64 * 365) return;
    const int b = idx / 365, n = idx % 365;
    float s = bias[n];
    #pragma unroll 4
    for (int sp = 0; sp < 64; ++sp)
        s += partial[((size_t)sp * 64 + b) * 384 + n];
    out[idx] = s;
}

// ---------------------------------------------------------------------------
extern "C" void kernel_launch(void* const* d_in, const int* in_sizes, int n_in,
                              void* d_out, int out_size, void* d_ws, size_t ws_size,
                              hipStream_t stream)
{
    const float* x   = (const float*)d_in[0];
    const float* fcw = (const float*)d_in[1];
    const float* fcb = (const float*)d_in[2];
    float* out = (float*)d_out;
    char* ws = (char*)d_ws;

    const size_t MS = (size_t)64 * 256 * 256 * 2;   // 8 MiB per matrix buffer
    ushort* w0 = (ushort*)(ws + 0 * MS);
    ushort* w1 = (ushort*)(ws + 1 * MS);
    ushort* w2 = (ushort*)(ws + 2 * MS);
    ushort* w3 = (ushort*)(ws + 3 * MS);
    ushort* w4 = (ushort*)(ws + 4 * MS);
    ushort* xc = (ushort*)(ws + 5 * MS);                     // 8 MiB (padded K=256)
    float*  var    = (float*)(ws + 6 * MS);                  // 65,536 B
    ushort* tri    = (ushort*)(ws + 6 * MS + 131072);        // 4,210,688 B
    float*  partial= (float*)(ws + 6 * MS + 131072 + 4210688);

    prep_kernel<<<4096, 256, 0, stream>>>(x, xc, var);

    // cov: Y0 -> w0, T0 -> w1
    gemm_ns<0><<<256, 256, 0, stream>>>(xc, nullptr, xc, w0, w1, var);
    // Y1 = Y0*T0 -> w2   (Z1 = T0 = w1)
    gemm_ns<4><<<256, 256, 0, stream>>>(w0, nullptr, w1, w2, nullptr, nullptr);
    // iter2 (Y=w2, Z=w1): T -> w0 ; Y' -> w3 ; Z' -> w4
    gemm_ns<1><<<256, 256, 0, stream>>>(w1, nullptr, w2, w0, nullptr, nullptr);
    gemm_ns<2><<<512, 256, 0, stream>>>(w2, w1, w0, w3, w4, nullptr);
    // iter3 (Y=w3, Z=w4): T -> w0 ; Y' -> w1 ; Z' -> w2
    gemm_ns<1><<<256, 256, 0, stream>>>(w4, nullptr, w3, w0, nullptr, nullptr);
    gemm_ns<2><<<512, 256, 0, stream>>>(w3, w4, w0, w1, w2, nullptr);
    // iter4 (Y=w1, Z=w2): T -> w0 ; Y' -> w3 ; Z' -> w4
    gemm_ns<1><<<256, 256, 0, stream>>>(w2, nullptr, w1, w0, nullptr, nullptr);
    gemm_ns<2><<<512, 256, 0, stream>>>(w1, w2, w0, w3, w4, nullptr);
    // iter5 (Y=w3, Z=w4): T -> w0 ; tri(Y*T*sqrt(trace)) -> tri
    gemm_ns<1><<<256, 256, 0, stream>>>(w4, nullptr, w3, w0, nullptr, nullptr);
    gemm_ns<3><<<192, 256, 0, stream>>>(w3, nullptr, w0, tri, nullptr, var);

    fc_gemm<<<dim3(6, 64), 256, 0, stream>>>(tri, fcw, partial);
    fc_reduce<<<(64 * 365 + 255) / 256, 256, 0, stream>>>(partial, fcb, out);
}